// Round 6
// baseline (208.863 us; speedup 1.0000x reference)
//
#include <hip/hip_runtime.h>

// out[b,o,i,j] = sum_c | sum_{ti,tj<=8} K[o,0,ti,tj] * x[b,c,(i+5-ti)&127,(j+5-tj)&127] |
// B=8 C=16 H=W=128 O=32. MFMA im2col (verified R3/R5 math):
//   per (b,c): D[m][o] = sum_k A[m][k]*Bk[k][o], k = ti*16+tj (tj pad 16, ti pad 10)
//   A[m][k] = x[i+5-ti][j+5-tj], j = 8*m + phase.  acc += |D| over c.
// LDS: column-reversed bf16 halo rows; m-tile = 16 px at stride 8 -> 16B-aligned
// ds_read_b128; odd phases via v_alignbit. One barrier per kernel (R5).
// R6: flatten (c,ck) -> 80 unrolled chunks, skew-2 rotating window prefetch
//     (covers LDS latency), explicit __builtin_amdgcn_alignbit (1 VALU/dword),
//     zero-C first MFMA of each channel (kills D zero-init), all LDS addresses
//     become immediates off one base VGPR. Staging/Bf/epilogue identical to R5.

typedef __attribute__((ext_vector_type(8)))  short  short8;
typedef __attribute__((ext_vector_type(4)))  float  float4v;
typedef __attribute__((ext_vector_type(4)))  unsigned int uint4v;

#define NROW 11                  // halo rows for 2 output rows: i0-4 .. i0+6
#define NCC  144                 // bf16 per LDS row = 288 B row stride
#define CHSZ (NROW * NCC)        // 1584 bf16 = 3168 B per channel
#define NSLOT (16 * NROW * 72)   // 12672 dword slots total

__device__ __forceinline__ unsigned short f2bf(float f) {
    union { float f; unsigned int u; } a; a.f = f;
    unsigned int u = a.u;
    u += 0x7fffu + ((u >> 16) & 1u);   // RNE
    return (unsigned short)(u >> 16);
}

// frag = 8 bf16 at byte offset 4*q_ (even) or 4*q_+2 (odd) within wnd[0..7]
#define FRAG_EVEN(q_) __builtin_bit_cast(short8, (uint4v){                    \
        wnd[(q_)+0], wnd[(q_)+1], wnd[(q_)+2], wnd[(q_)+3]})
#define FRAG_ODD(q_)  __builtin_bit_cast(short8, (uint4v){                    \
        __builtin_amdgcn_alignbit(wnd[(q_)+1], wnd[(q_)+0], 16),              \
        __builtin_amdgcn_alignbit(wnd[(q_)+2], wnd[(q_)+1], 16),              \
        __builtin_amdgcn_alignbit(wnd[(q_)+3], wnd[(q_)+2], 16),              \
        __builtin_amdgcn_alignbit(wnd[(q_)+4], wnd[(q_)+3], 16)})

// decode dword slot s -> loads + LDS dword index (verified R5 staging)
#define LOAD_SLOT(s_, v0_, v1_, ad_)                                         \
    {                                                                        \
        int ch  = (s_) / 792;                                                \
        int rem = (s_) - 792 * ch;                                           \
        int rr  = rem / 72;                                                  \
        int ccd = rem - 72 * rr;                                             \
        int cc  = 2 * ccd;                                                   \
        int xrow = (i0 - 4 + rr) & 127;                                      \
        const float* xp = xb + (ch << 14) + (xrow << 7);                     \
        v0_ = xp[(132 - cc) & 127];                                          \
        v1_ = xp[(131 - cc) & 127];                                          \
        ad_ = ch * CHSZ + rr * NCC + cc;                                     \
    }

__global__ __launch_bounds__(512, 4)
void optical_conv_69698729279498(const float* __restrict__ x,
                                 const float* __restrict__ kern,
                                 float* __restrict__ out) {
    __shared__ __align__(16) unsigned short ldsb[16 * CHSZ];  // 50688 B

    const int tid = threadIdx.x;
    const int l   = tid & 63;
    const int w   = tid >> 6;       // wave 0..7
    const int h   = w & 1;          // phase-half: p' = 4h + pp
    const int oh  = (w >> 1) & 1;   // o-half
    const int rh  = w >> 2;         // row within block's 2-row tile
    const int i0  = blockIdx.x * 2; // first output row of tile
    const int b   = blockIdx.y;     // batch 0..7

    const int lk   = l & 15;        // A m-index / B,D o-index
    const int g    = (l >> 4) & 1;  // tj half for A
    const int hi32 = l >> 5;        // ti parity within chunk for A
    const int g2   = l >> 4;        // quad 0..3
    const int o    = oh * 16 + lk;

    const float* xb = x + ((size_t)b << 18);   // batch slice [16,128,128]

    // ---- staging: two register-bounded groups (R5 verified, no spills)
    float v0a[13], v1a[13]; int aa[13];
#pragma unroll
    for (int k = 0; k < 13; ++k) {
        int s = tid + 512 * k;                 // < 12672 always
        LOAD_SLOT(s, v0a[k], v1a[k], aa[k]);
    }
    float v0b[12], v1b[12]; int ab[12];
#pragma unroll
    for (int k = 0; k < 12; ++k) {
        int s = tid + 512 * (13 + k);
        if (s > NSLOT - 1) s = NSLOT - 1;      // clamped dups write identical data
        LOAD_SLOT(s, v0b[k], v1b[k], ab[k]);
    }
#pragma unroll
    for (int k = 0; k < 13; ++k) {
        unsigned int pk2 = (unsigned int)f2bf(v0a[k]) | ((unsigned int)f2bf(v1a[k]) << 16);
        *(unsigned int*)&ldsb[aa[k]] = pk2;
    }
#pragma unroll
    for (int k = 0; k < 12; ++k) {
        unsigned int pk2 = (unsigned int)f2bf(v0b[k]) | ((unsigned int)f2bf(v1b[k]) << 16);
        *(unsigned int*)&ldsb[ab[k]] = pk2;
    }

    // ---- B fragments: Bk[k=ti*16+tj][o], zeros for ti>8 or tj>8
    short8 Bf[5];
#pragma unroll
    for (int ck = 0; ck < 5; ++ck) {
        const int ti  = 2 * ck + (g2 >> 1);
        const int tj0 = (g2 & 1) * 8;
        unsigned int pk[4];
#pragma unroll
        for (int ee = 0; ee < 4; ++ee) {
            int tj_a = tj0 + 2 * ee, tj_b = tj_a + 1;
            float va = (ti <= 8 && tj_a <= 8) ? kern[o * 1296 + ti * 9 + tj_a] : 0.f;
            float vb = (ti <= 8 && tj_b <= 8) ? kern[o * 1296 + ti * 9 + tj_b] : 0.f;
            pk[ee] = (unsigned int)f2bf(va) | ((unsigned int)f2bf(vb) << 16);
        }
        uint4v bv; bv.x = pk[0]; bv.y = pk[1]; bv.z = pk[2]; bv.w = pk[3];
        Bf[ck] = __builtin_bit_cast(short8, bv);
    }

    __syncthreads();   // the ONLY barrier in the kernel

    // per-lane window base; chunk (c,ck) lives at wbase + c*3168 - ck*576
    const char* wbase = (const char*)ldsb
                      + (240 - 16 * lk + 16 * g) + (9 + rh - hi32) * 288;

    float4v acc[4];
#pragma unroll
    for (int pp = 0; pp < 4; ++pp) acc[pp] = (float4v){0.f, 0.f, 0.f, 0.f};
    const float4v zero4 = (float4v){0.f, 0.f, 0.f, 0.f};

    uint4v bufA[3], bufB[3];
    float4v D[4];

#define LDWIN(t_, sl_)                                                       \
    {                                                                        \
        const char* p_ = wbase + (((t_) / 5) * 3168 - ((t_) % 5) * 576);     \
        bufA[sl_] = *(const uint4v*)p_;                                      \
        bufB[sl_] = *(const uint4v*)(p_ + 16);                               \
    }

    LDWIN(0, 0);
    LDWIN(1, 1);

#pragma unroll
    for (int t = 0; t < 80; ++t) {
        if (t + 2 < 80) LDWIN(t + 2, (t + 2) % 3);
        const int ck = t % 5;
        uint4v w0 = bufA[t % 3], w1 = bufB[t % 3];
        unsigned int wnd[8] = {w0.x, w0.y, w0.z, w0.w, w1.x, w1.y, w1.z, w1.w};
        if (h == 0) {   // phases 0..3 -> frag byte offsets 14,12,10,8
            short8 f0 = FRAG_ODD(3),  f1 = FRAG_EVEN(3);
            short8 f2 = FRAG_ODD(2),  f3 = FRAG_EVEN(2);
            D[0] = __builtin_amdgcn_mfma_f32_16x16x32_bf16(f0, Bf[ck], ck ? D[0] : zero4, 0, 0, 0);
            D[1] = __builtin_amdgcn_mfma_f32_16x16x32_bf16(f1, Bf[ck], ck ? D[1] : zero4, 0, 0, 0);
            D[2] = __builtin_amdgcn_mfma_f32_16x16x32_bf16(f2, Bf[ck], ck ? D[2] : zero4, 0, 0, 0);
            D[3] = __builtin_amdgcn_mfma_f32_16x16x32_bf16(f3, Bf[ck], ck ? D[3] : zero4, 0, 0, 0);
        } else {        // phases 4..7 -> frag byte offsets 6,4,2,0
            short8 f0 = FRAG_ODD(1),  f1 = FRAG_EVEN(1);
            short8 f2 = FRAG_ODD(0),  f3 = FRAG_EVEN(0);
            D[0] = __builtin_amdgcn_mfma_f32_16x16x32_bf16(f0, Bf[ck], ck ? D[0] : zero4, 0, 0, 0);
            D[1] = __builtin_amdgcn_mfma_f32_16x16x32_bf16(f1, Bf[ck], ck ? D[1] : zero4, 0, 0, 0);
            D[2] = __builtin_amdgcn_mfma_f32_16x16x32_bf16(f2, Bf[ck], ck ? D[2] : zero4, 0, 0, 0);
            D[3] = __builtin_amdgcn_mfma_f32_16x16x32_bf16(f3, Bf[ck], ck ? D[3] : zero4, 0, 0, 0);
        }
        if (ck == 4) {
#pragma unroll
            for (int pp = 0; pp < 4; ++pp)
#pragma unroll
                for (int e = 0; e < 4; ++e) acc[pp][e] += fabsf(D[pp][e]);
        }
    }

    // ---- epilogue: lane holds o = oh*16+lk, row i0+rh, pixels j = 32*g2 + 8*e + p'
    const int i = i0 + rh;
    float* ob = out + ((((size_t)(b * 32 + o)) * 128 + i) << 7);
#pragma unroll
    for (int pp = 0; pp < 4; ++pp) {
        const int pprime = 4 * h + pp;
#pragma unroll
        for (int e = 0; e < 4; ++e)
            ob[32 * g2 + 8 * e + pprime] = acc[pp][e];
    }
}

extern "C" void kernel_launch(void* const* d_in, const int* in_sizes, int n_in,
                              void* d_out, int out_size, void* d_ws, size_t ws_size,
                              hipStream_t stream) {
    const float* x = (const float*)d_in[0];      // [8,16,128,128]
    const float* kern = (const float*)d_in[1];   // [32,16,9,9]
    float* out = (float*)d_out;                  // [8,32,128,128]
    dim3 block(512);
    dim3 grid(64, 8);   // 2 output rows per block x 8 batches = 512 blocks (2/CU)
    hipLaunchKernelGGL(optical_conv_69698729279498, grid, block, 0, stream,
                       x, kern, out);
}

// Round 7
// 106.924 us; speedup vs baseline: 1.9534x; 1.9534x over previous
//
#include <hip/hip_runtime.h>

// out[b,o,i,j] = sum_c | sum_{ti,tj<=8} K[o,0,ti,tj] * x[b,c,(i+5-ti)&127,(j+5-tj)&127] |
// B=8 C=16 H=W=128 O=32. MFMA im2col (verified R3/R5 math):
//   per (b,c): D[m][o] = sum_k A[m][k]*Bk[k][o], k = ti*16+tj (tj pad 16, ti pad 10)
//   A[m][k] = x[i+5-ti][j+5-tj], j = 8*m + phase.  acc += |D| over c.
// LDS: column-reversed bf16 halo rows; m-tile = 16 px at stride 8 -> 16B-aligned
// ds_read_b128; odd phases via alignbit. One staging barrier (R5).
// R7 (base = R5, the 43us/48-VGPR no-spill kernel; R6's rotating-buffer scratch
//     disaster reverted):
//   - 1 output row/block, 512 threads, c-split: waves 0-3 chan 0-7, waves 4-7
//     chan 8-15; stride-17 LDS reduction combine. LDS 46 KB -> 3 blocks/CU.
//   - explicit __builtin_amdgcn_alignbit for odd-phase frags.
//   - zero-C first MFMA per channel (no D zero-init).
//   All array indices compile-time inside a 5-way unrolled ck loop (R5-proven).

typedef __attribute__((ext_vector_type(8)))  short  short8;
typedef __attribute__((ext_vector_type(4)))  float  float4v;
typedef __attribute__((ext_vector_type(4)))  unsigned int uint4v;

#define NROW 10                  // halo rows for 1 output row: i-4 .. i+5
#define NCC  144                 // bf16 per LDS row = 288 B row stride
#define CHSZ (NROW * NCC)        // 1440 bf16 = 2880 B per channel
#define NSLOT (16 * NROW * 72)   // 11520 dword slots total

__device__ __forceinline__ unsigned short f2bf(float f) {
    union { float f; unsigned int u; } a; a.f = f;
    unsigned int u = a.u;
    u += 0x7fffu + ((u >> 16) & 1u);   // RNE
    return (unsigned short)(u >> 16);
}

#if __has_builtin(__builtin_amdgcn_alignbit)
#define ALIGN16(hi_, lo_) __builtin_amdgcn_alignbit((hi_), (lo_), 16)
#else
#define ALIGN16(hi_, lo_) \
    (unsigned int)((((unsigned long long)(hi_) << 32) | (lo_)) >> 16)
#endif

// frag = 8 bf16 at byte offset 4*q_ (even) or 4*q_+2 (odd) within wnd[0..7]
#define FRAG_EVEN(q_) __builtin_bit_cast(short8, (uint4v){                    \
        wnd[(q_)+0], wnd[(q_)+1], wnd[(q_)+2], wnd[(q_)+3]})
#define FRAG_ODD(q_)  __builtin_bit_cast(short8, (uint4v){                    \
        ALIGN16(wnd[(q_)+1], wnd[(q_)+0]),                                    \
        ALIGN16(wnd[(q_)+2], wnd[(q_)+1]),                                    \
        ALIGN16(wnd[(q_)+3], wnd[(q_)+2]),                                    \
        ALIGN16(wnd[(q_)+4], wnd[(q_)+3])})

// decode dword slot s -> loads + LDS dword index (R5-verified staging, 1-row)
#define LOAD_SLOT(s_, v0_, v1_, ad_)                                         \
    {                                                                        \
        int ch  = (s_) / 720;                                                \
        int rem = (s_) - 720 * ch;                                           \
        int rr  = rem / 72;                                                  \
        int ccd = rem - 72 * rr;                                             \
        int cc  = 2 * ccd;                                                   \
        int xrow = (i - 4 + rr) & 127;                                       \
        const float* xp = xb + (ch << 14) + (xrow << 7);                     \
        v0_ = xp[(132 - cc) & 127];                                          \
        v1_ = xp[(131 - cc) & 127];                                          \
        ad_ = ch * CHSZ + rr * NCC + cc;                                     \
    }

__global__ __launch_bounds__(512, 5)
void optical_conv_69698729279498(const float* __restrict__ x,
                                 const float* __restrict__ kern,
                                 float* __restrict__ out) {
    __shared__ __align__(16) unsigned short ldsb[16 * CHSZ];  // 46080 B

    const int tid = threadIdx.x;
    const int l   = tid & 63;
    const int w   = tid >> 6;       // wave 0..7
    const int h   = w & 1;          // phase-half: p' = 4h + pp
    const int oh  = (w >> 1) & 1;   // o-half
    const int cg  = w >> 2;         // channel group 0..1
    const int i   = blockIdx.x;     // output row 0..127
    const int b   = blockIdx.y;     // batch 0..7

    const int lk   = l & 15;        // A m-index / B,D o-index
    const int g    = (l >> 4) & 1;  // tj half for A
    const int hi32 = l >> 5;        // ti parity within chunk for A
    const int g2   = l >> 4;        // quad 0..3
    const int o    = oh * 16 + lk;

    const float* xb = x + ((size_t)b << 18);   // batch slice [16,128,128]

    // ---- staging: 23 slots/thread in two register-bounded groups (no spills)
    float v0a[12], v1a[12]; int aa[12];
#pragma unroll
    for (int k = 0; k < 12; ++k) {
        int s = tid + 512 * k;                 // <= 511+5632 < 11520 always
        LOAD_SLOT(s, v0a[k], v1a[k], aa[k]);
    }
    float v0b[11], v1b[11]; int ab[11];
#pragma unroll
    for (int k = 0; k < 11; ++k) {
        int s = tid + 512 * (12 + k);
        if (s > NSLOT - 1) s = NSLOT - 1;      // clamped dups write identical data
        LOAD_SLOT(s, v0b[k], v1b[k], ab[k]);
    }
#pragma unroll
    for (int k = 0; k < 12; ++k) {
        unsigned int pk2 = (unsigned int)f2bf(v0a[k]) | ((unsigned int)f2bf(v1a[k]) << 16);
        *(unsigned int*)&ldsb[aa[k]] = pk2;
    }
#pragma unroll
    for (int k = 0; k < 11; ++k) {
        unsigned int pk2 = (unsigned int)f2bf(v0b[k]) | ((unsigned int)f2bf(v1b[k]) << 16);
        *(unsigned int*)&ldsb[ab[k]] = pk2;
    }

    // ---- B fragments: Bk[k=ti*16+tj][o], zeros for ti>8 or tj>8
    short8 Bf[5];
#pragma unroll
    for (int ck = 0; ck < 5; ++ck) {
        const int ti  = 2 * ck + (g2 >> 1);
        const int tj0 = (g2 & 1) * 8;
        unsigned int pk[4];
#pragma unroll
        for (int ee = 0; ee < 4; ++ee) {
            int tj_a = tj0 + 2 * ee, tj_b = tj_a + 1;
            float va = (ti <= 8 && tj_a <= 8) ? kern[o * 1296 + ti * 9 + tj_a] : 0.f;
            float vb = (ti <= 8 && tj_b <= 8) ? kern[o * 1296 + ti * 9 + tj_b] : 0.f;
            pk[ee] = (unsigned int)f2bf(va) | ((unsigned int)f2bf(vb) << 16);
        }
        uint4v bv; bv.x = pk[0]; bv.y = pk[1]; bv.z = pk[2]; bv.w = pk[3];
        Bf[ck] = __builtin_bit_cast(short8, bv);
    }

    __syncthreads();   // staging barrier

    float4v acc[4];
#pragma unroll
    for (int pp = 0; pp < 4; ++pp) acc[pp] = (float4v){0.f, 0.f, 0.f, 0.f};
    const float4v zero4 = (float4v){0.f, 0.f, 0.f, 0.f};

    // per-lane base: chunk ck of channel c lives at lb + c*2880 + (8-2ck)*288
    // (row r = 9 - ti, ti = 2ck + hi32; col = 240 - 16lk + 16g)
    const char* lb = (const char*)ldsb
                   + (240 - 16 * lk + 16 * g) + (1 - hi32) * 288
                   + cg * 8 * 2880;

    for (int c = 0; c < 8; ++c) {
        float4v D[4];
#pragma unroll
        for (int ck = 0; ck < 5; ++ck) {
            const char* p = lb + (8 - 2 * ck) * 288;
            uint4v w0 = *(const uint4v*)p;
            uint4v w1 = *(const uint4v*)(p + 16);
            unsigned int wnd[8] = {w0.x, w0.y, w0.z, w0.w, w1.x, w1.y, w1.z, w1.w};
            if (h == 0) {   // phases 0..3 -> frag byte offsets 14,12,10,8
                short8 f0 = FRAG_ODD(3),  f1 = FRAG_EVEN(3);
                short8 f2 = FRAG_ODD(2),  f3 = FRAG_EVEN(2);
                D[0] = __builtin_amdgcn_mfma_f32_16x16x32_bf16(f0, Bf[ck], ck ? D[0] : zero4, 0, 0, 0);
                D[1] = __builtin_amdgcn_mfma_f32_16x16x32_bf16(f1, Bf[ck], ck ? D[1] : zero4, 0, 0, 0);
                D[2] = __builtin_amdgcn_mfma_f32_16x16x32_bf16(f2, Bf[ck], ck ? D[2] : zero4, 0, 0, 0);
                D[3] = __builtin_amdgcn_mfma_f32_16x16x32_bf16(f3, Bf[ck], ck ? D[3] : zero4, 0, 0, 0);
            } else {        // phases 4..7 -> frag byte offsets 6,4,2,0
                short8 f0 = FRAG_ODD(1),  f1 = FRAG_EVEN(1);
                short8 f2 = FRAG_ODD(0),  f3 = FRAG_EVEN(0);
                D[0] = __builtin_amdgcn_mfma_f32_16x16x32_bf16(f0, Bf[ck], ck ? D[0] : zero4, 0, 0, 0);
                D[1] = __builtin_amdgcn_mfma_f32_16x16x32_bf16(f1, Bf[ck], ck ? D[1] : zero4, 0, 0, 0);
                D[2] = __builtin_amdgcn_mfma_f32_16x16x32_bf16(f2, Bf[ck], ck ? D[2] : zero4, 0, 0, 0);
                D[3] = __builtin_amdgcn_mfma_f32_16x16x32_bf16(f3, Bf[ck], ck ? D[3] : zero4, 0, 0, 0);
            }
        }
#pragma unroll
        for (int pp = 0; pp < 4; ++pp)
#pragma unroll
            for (int e = 0; e < 4; ++e) acc[pp][e] += fabsf(D[pp][e]);
        lb += 2880;
    }

    // ---- cross-wave c-split reduction (stride-17 floats: conflict-free-ish)
    __syncthreads();   // all LDS x-reads done; safe to overwrite
    float* red = (float*)ldsb;
    const int rbase = (((w & 3) << 6) + l) * 17;
    if (cg == 1) {
#pragma unroll
        for (int pp = 0; pp < 4; ++pp)
#pragma unroll
            for (int e = 0; e < 4; ++e) red[rbase + 4 * pp + e] = acc[pp][e];
    }
    __syncthreads();
    if (cg == 0) {
#pragma unroll
        for (int pp = 0; pp < 4; ++pp)
#pragma unroll
            for (int e = 0; e < 4; ++e) acc[pp][e] += red[rbase + 4 * pp + e];
        // epilogue: lane holds o = oh*16+lk, row i, pixels j = 32*g2 + 8*e + p'
        float* ob = out + ((((size_t)(b * 32 + o)) * 128 + i) << 7);
#pragma unroll
        for (int pp = 0; pp < 4; ++pp) {
            const int pprime = 4 * h + pp;
#pragma unroll
            for (int e = 0; e < 4; ++e)
                ob[32 * g2 + 8 * e + pprime] = acc[pp][e];
        }
    }
}

extern "C" void kernel_launch(void* const* d_in, const int* in_sizes, int n_in,
                              void* d_out, int out_size, void* d_ws, size_t ws_size,
                              hipStream_t stream) {
    const float* x = (const float*)d_in[0];      // [8,16,128,128]
    const float* kern = (const float*)d_in[1];   // [32,16,9,9]
    float* out = (float*)d_out;                  // [8,32,128,128]
    dim3 block(512);
    dim3 grid(128, 8);   // 1 output row per block x 8 batches = 1024 blocks
    hipLaunchKernelGGL(optical_conv_69698729279498, grid, block, 0, stream,
                       x, kern, out);
}

// Round 8
// 99.552 us; speedup vs baseline: 2.0980x; 1.0740x over previous
//
#include <hip/hip_runtime.h>

// out[b,o,i,j] = sum_c | sum_{ti,tj<=8} K[o,0,ti,tj] * x[b,c,(i+5-ti)&127,(j+5-tj)&127] |
// B=8 C=16 H=W=128 O=32. MFMA im2col (verified R3/R5 math):
//   per (b,c): D[m][o] = sum_k A[m][k]*Bk[k][o], k = ti*16+tj (tj pad 16, ti pad 10)
//   A[m][k] = x[i+5-ti][j+5-tj], j = 8*m + phase.  acc += |D| over c.
// R8: staging cost hoisted into prep kernels (R5/R7 showed staging VALU+latency
//     dominates, not MFMA/LDS):
//   prep_x: x -> column-reversed bf16, rows 0..8 replicated after 127 (138
//           rows/ch) so every 11-row halo window is ONE contiguous 3168-B slab
//           in the exact LDS byte layout.
//   prep_b: per-lane packed MFMA B-fragments (2x5x64 lanes x 16 B).
//   main:   R5 structure (2 rows/block, 512 thr, one barrier) but staging is
//           8 x global_load_lds_dwordx4 per wave (DMA, ~zero VALU), Bf is 5
//           coalesced dwordx4 loads. Compute = R7's verified alignbit + zero-C.

typedef __attribute__((ext_vector_type(8)))  short  short8;
typedef __attribute__((ext_vector_type(4)))  float  float4v;
typedef __attribute__((ext_vector_type(4)))  unsigned int uint4v;

#define XR_ROWS 138                   // 128 + 9 replicated + 1 pad
#define XR_RDW  72                    // dwords per row (144 bf16 = 288 B)
#define XR_CH_DW (XR_ROWS * XR_RDW)   // 9936 dwords per channel
#define XR_TOT_DW (128 * XR_CH_DW)    // 1,271,808 dwords
#define BPRE_OFF ((size_t)128 * XR_ROWS * 288)   // 5,087,232 B
#define CHB 3168                      // LDS bytes per channel (11 rows x 288)

__device__ __forceinline__ unsigned int f2bf(float f) {
    union { float f; unsigned int u; } a; a.f = f;
    unsigned int u = a.u;
    u += 0x7fffu + ((u >> 16) & 1u);   // RNE
    return u >> 16;
}

#if __has_builtin(__builtin_amdgcn_alignbit)
#define ALIGN16(hi_, lo_) __builtin_amdgcn_alignbit((hi_), (lo_), 16)
#else
#define ALIGN16(hi_, lo_) \
    (unsigned int)((((unsigned long long)(hi_) << 32) | (lo_)) >> 16)
#endif

#define FRAG_EVEN(q_) __builtin_bit_cast(short8, (uint4v){                    \
        wnd[(q_)+0], wnd[(q_)+1], wnd[(q_)+2], wnd[(q_)+3]})
#define FRAG_ODD(q_)  __builtin_bit_cast(short8, (uint4v){                    \
        ALIGN16(wnd[(q_)+1], wnd[(q_)+0]),                                    \
        ALIGN16(wnd[(q_)+2], wnd[(q_)+1]),                                    \
        ALIGN16(wnd[(q_)+3], wnd[(q_)+2]),                                    \
        ALIGN16(wnd[(q_)+4], wnd[(q_)+3])})

__device__ __forceinline__ void gload_lds16(const void* g, void* l) {
    __builtin_amdgcn_global_load_lds(
        (const __attribute__((address_space(1))) unsigned int*)g,
        (__attribute__((address_space(3))) unsigned int*)l, 16, 0, 0);
}

// ---- prep_x: xr[bc][r][cc] = f2bf(x[bc][r&127][(132-2*ccd -{0,1})&127]) packed
__global__ __launch_bounds__(256)
void optical_prep_x_69698729279498(const float* __restrict__ x,
                                   unsigned int* __restrict__ xr) {
    for (int idx = blockIdx.x * 256 + threadIdx.x; idx < XR_TOT_DW;
         idx += gridDim.x * 256) {
        int bc  = idx / XR_CH_DW;
        int rem = idx - bc * XR_CH_DW;
        int r   = rem / XR_RDW;
        int ccd = rem - r * XR_RDW;
        int cc  = 2 * ccd;
        const float* xp = x + (bc << 14) + ((r & 127) << 7);
        float v0 = xp[(132 - cc) & 127];
        float v1 = xp[(131 - cc) & 127];
        xr[idx] = f2bf(v0) | (f2bf(v1) << 16);
    }
}

// ---- prep_b: packed per-lane B fragments, layout [oh][ck][lane] x 16 B
__global__ __launch_bounds__(64)
void optical_prep_b_69698729279498(const float* __restrict__ kern,
                                   uint4v* __restrict__ bpre) {
    const int l  = threadIdx.x;
    const int lk = l & 15;
    const int g2 = l >> 4;
    for (int oh = 0; oh < 2; ++oh) {
        const int o = oh * 16 + lk;
        for (int ck = 0; ck < 5; ++ck) {
            const int ti  = 2 * ck + (g2 >> 1);
            const int tj0 = (g2 & 1) * 8;
            unsigned int pk[4];
#pragma unroll
            for (int ee = 0; ee < 4; ++ee) {
                int tj_a = tj0 + 2 * ee, tj_b = tj_a + 1;
                float va = (ti <= 8 && tj_a <= 8) ? kern[o * 1296 + ti * 9 + tj_a] : 0.f;
                float vb = (ti <= 8 && tj_b <= 8) ? kern[o * 1296 + ti * 9 + tj_b] : 0.f;
                pk[ee] = f2bf(va) | (f2bf(vb) << 16);
            }
            bpre[(oh * 5 + ck) * 64 + l] = (uint4v){pk[0], pk[1], pk[2], pk[3]};
        }
    }
}

// ---- main
__global__ __launch_bounds__(512, 4)
void optical_conv_69698729279498(const unsigned int* __restrict__ xr,
                                 const uint4v* __restrict__ bpre,
                                 float* __restrict__ out) {
    __shared__ __align__(16) unsigned short ldsb[16 * (CHB / 2)];  // 50688 B

    const int tid = threadIdx.x;
    const int l   = tid & 63;
    const int w   = tid >> 6;        // wave 0..7
    const int h   = w & 1;           // phase-half: p' = 4h + pp
    const int oh  = (w >> 1) & 1;    // o-half
    const int rh  = w >> 2;          // row within block's 2-row tile
    const int i0  = blockIdx.x * 2;  // first output row of tile
    const int b   = blockIdx.y;      // batch 0..7

    const int lk   = l & 15;         // A m-index / B,D o-index
    const int g    = (l >> 4) & 1;   // tj half for A
    const int hi32 = l >> 5;         // ti parity within chunk for A
    const int g2   = l >> 4;         // quad 0..3
    const int o    = oh * 16 + lk;

    // ---- staging: wave w DMAs channels 2w, 2w+1 (contiguous slabs in xr)
    const int wstart = (i0 >= 4) ? (i0 - 4) : (i0 + 124);
    const char* xr8 = (const char*)xr;
#pragma unroll
    for (int cw = 0; cw < 2; ++cw) {
        const int ch = 2 * w + cw;
        const char* src = xr8 + ((size_t)((b * 16 + ch) * XR_ROWS + wstart)) * 288;
        char* dst = (char*)ldsb + ch * CHB;
        gload_lds16(src + 0 * 1024 + l * 16, dst + 0 * 1024);
        gload_lds16(src + 1 * 1024 + l * 16, dst + 1 * 1024);
        gload_lds16(src + 2 * 1024 + l * 16, dst + 2 * 1024);
        if (l < 6)   // tail: 3168 - 3072 = 96 B
            gload_lds16(src + 3072 + l * 16, dst + 3072);
    }

    // ---- B fragments: 5 coalesced dwordx4 loads
    short8 Bf[5];
#pragma unroll
    for (int ck = 0; ck < 5; ++ck)
        Bf[ck] = __builtin_bit_cast(short8, bpre[(oh * 5 + ck) * 64 + l]);

    __syncthreads();   // the ONLY barrier (drains the global_load_lds queue)

    float4v acc[4];
#pragma unroll
    for (int pp = 0; pp < 4; ++pp) acc[pp] = (float4v){0.f, 0.f, 0.f, 0.f};
    const float4v zero4 = (float4v){0.f, 0.f, 0.f, 0.f};

    // chunk ck of channel c: byte (9 - 2ck - hi32 + rh)*288 + 240 - 16lk + 16g
    const char* lb = (const char*)ldsb
                   + (240 - 16 * lk + 16 * g) + (1 - hi32 + rh) * 288;

    for (int c = 0; c < 16; ++c) {
        float4v D[4];
#pragma unroll
        for (int ck = 0; ck < 5; ++ck) {
            const char* p = lb + (8 - 2 * ck) * 288;
            uint4v w0 = *(const uint4v*)p;
            uint4v w1 = *(const uint4v*)(p + 16);
            unsigned int wnd[8] = {w0.x, w0.y, w0.z, w0.w, w1.x, w1.y, w1.z, w1.w};
            if (h == 0) {   // phases 0..3 -> frag byte offsets 14,12,10,8
                short8 f0 = FRAG_ODD(3),  f1 = FRAG_EVEN(3);
                short8 f2 = FRAG_ODD(2),  f3 = FRAG_EVEN(2);
                D[0] = __builtin_amdgcn_mfma_f32_16x16x32_bf16(f0, Bf[ck], ck ? D[0] : zero4, 0, 0, 0);
                D[1] = __builtin_amdgcn_mfma_f32_16x16x32_bf16(f1, Bf[ck], ck ? D[1] : zero4, 0, 0, 0);
                D[2] = __builtin_amdgcn_mfma_f32_16x16x32_bf16(f2, Bf[ck], ck ? D[2] : zero4, 0, 0, 0);
                D[3] = __builtin_amdgcn_mfma_f32_16x16x32_bf16(f3, Bf[ck], ck ? D[3] : zero4, 0, 0, 0);
            } else {        // phases 4..7 -> frag byte offsets 6,4,2,0
                short8 f0 = FRAG_ODD(1),  f1 = FRAG_EVEN(1);
                short8 f2 = FRAG_ODD(0),  f3 = FRAG_EVEN(0);
                D[0] = __builtin_amdgcn_mfma_f32_16x16x32_bf16(f0, Bf[ck], ck ? D[0] : zero4, 0, 0, 0);
                D[1] = __builtin_amdgcn_mfma_f32_16x16x32_bf16(f1, Bf[ck], ck ? D[1] : zero4, 0, 0, 0);
                D[2] = __builtin_amdgcn_mfma_f32_16x16x32_bf16(f2, Bf[ck], ck ? D[2] : zero4, 0, 0, 0);
                D[3] = __builtin_amdgcn_mfma_f32_16x16x32_bf16(f3, Bf[ck], ck ? D[3] : zero4, 0, 0, 0);
            }
        }
#pragma unroll
        for (int pp = 0; pp < 4; ++pp)
#pragma unroll
            for (int e = 0; e < 4; ++e) acc[pp][e] += fabsf(D[pp][e]);
        lb += CHB;
    }

    // ---- epilogue: lane holds o = oh*16+lk, row i0+rh, pixels j = 32g2+8e+p'
    const int i = i0 + rh;
    float* ob = out + ((((size_t)(b * 32 + o)) * 128 + i) << 7);
#pragma unroll
    for (int pp = 0; pp < 4; ++pp) {
        const int pprime = 4 * h + pp;
#pragma unroll
        for (int e = 0; e < 4; ++e)
            ob[32 * g2 + 8 * e + pprime] = acc[pp][e];
    }
}

extern "C" void kernel_launch(void* const* d_in, const int* in_sizes, int n_in,
                              void* d_out, int out_size, void* d_ws, size_t ws_size,
                              hipStream_t stream) {
    const float* x = (const float*)d_in[0];      // [8,16,128,128]
    const float* kern = (const float*)d_in[1];   // [32,16,9,9]
    float* out = (float*)d_out;                  // [8,32,128,128]
    unsigned int* xr = (unsigned int*)d_ws;                        // 5.09 MB
    uint4v* bpre = (uint4v*)((char*)d_ws + BPRE_OFF);              // +10 KB

    hipLaunchKernelGGL(optical_prep_x_69698729279498, dim3(4096), dim3(256),
                       0, stream, x, xr);
    hipLaunchKernelGGL(optical_prep_b_69698729279498, dim3(1), dim3(64),
                       0, stream, kern, bpre);
    hipLaunchKernelGGL(optical_conv_69698729279498, dim3(64, 8), dim3(512),
                       0, stream, xr, bpre, out);
}

// Round 9
// 94.749 us; speedup vs baseline: 2.2044x; 1.0507x over previous
//
#include <hip/hip_runtime.h>

// out[b,o,i,j] = sum_c | sum_{ti,tj<=8} K[o,0,ti,tj] * x[b,c,(i+5-ti)&127,(j+5-tj)&127] |
// B=8 C=16 H=W=128 O=32. MFMA im2col (verified R3/R5/R8 math):
//   per (b,c): D[m][o] = sum_k A[m][k]*Bk[k][o], k = ti*16+tj (tj pad 16, ti pad 10)
//   A[m][k] = x[i+5-ti][j+5-tj], j = 8*m + phase.  acc += |D| over c.
// R9: h-merge — R8's four waves (h x oh) read byte-identical LDS windows; one
//     wave now computes all 8 phases per window (8 MFMAs, D[8]) halving LDS
//     traffic (the dominant pipe). Block 256 thr (4 waves = oh x rh), 2 rows,
//     512 blocks. Staging DMA + prepacked xr/bpre identical to R8 (passed).
//     prep_b folded into prep_x (one launch fewer). All private-array indices
//     compile-time under full unroll (R6 scratch lesson).

typedef __attribute__((ext_vector_type(8)))  short  short8;
typedef __attribute__((ext_vector_type(4)))  float  float4v;
typedef __attribute__((ext_vector_type(4)))  unsigned int uint4v;

#define XR_ROWS 138                   // 128 + 9 replicated + 1 pad
#define XR_RDW  72                    // dwords per row (144 bf16 = 288 B)
#define XR_CH_DW (XR_ROWS * XR_RDW)   // 9936 dwords per channel
#define XR_TOT_DW (128 * XR_CH_DW)    // 1,271,808 dwords
#define BPRE_OFF ((size_t)128 * XR_ROWS * 288)   // 5,087,232 B (16B aligned)
#define CHB 3168                      // LDS bytes per channel (11 rows x 288)
#define PREP_BLOCKS 2048
#define PREP_STRIDE (PREP_BLOCKS * 256)

__device__ __forceinline__ unsigned int f2bf(float f) {
    union { float f; unsigned int u; } a; a.f = f;
    unsigned int u = a.u;
    u += 0x7fffu + ((u >> 16) & 1u);   // RNE
    return u >> 16;
}

#if __has_builtin(__builtin_amdgcn_alignbit)
#define ALIGN16(hi_, lo_) __builtin_amdgcn_alignbit((hi_), (lo_), 16)
#else
#define ALIGN16(hi_, lo_) \
    (unsigned int)((((unsigned long long)(hi_) << 32) | (lo_)) >> 16)
#endif

#define FRAG_EVEN(q_) __builtin_bit_cast(short8, (uint4v){                    \
        wnd[(q_)+0], wnd[(q_)+1], wnd[(q_)+2], wnd[(q_)+3]})
#define FRAG_ODD(q_)  __builtin_bit_cast(short8, (uint4v){                    \
        ALIGN16(wnd[(q_)+1], wnd[(q_)+0]),                                    \
        ALIGN16(wnd[(q_)+2], wnd[(q_)+1]),                                    \
        ALIGN16(wnd[(q_)+3], wnd[(q_)+2]),                                    \
        ALIGN16(wnd[(q_)+4], wnd[(q_)+3])})

__device__ __forceinline__ void gload_lds16(const void* g, void* l) {
    __builtin_amdgcn_global_load_lds(
        (const __attribute__((address_space(1))) unsigned int*)g,
        (__attribute__((address_space(3))) unsigned int*)l, 16, 0, 0);
}

// ---- prep: xr = column-reversed bf16 x with replicated wrap rows; plus
//            per-lane packed B fragments (last block).
__global__ __launch_bounds__(256)
void optical_prep_69698729279498(const float* __restrict__ x,
                                 const float* __restrict__ kern,
                                 unsigned int* __restrict__ xr,
                                 uint4v* __restrict__ bpre) {
    if (blockIdx.x == PREP_BLOCKS) {
        const int l = threadIdx.x;
        if (l < 64) {
            const int lk = l & 15;
            const int g2 = l >> 4;
            for (int oh = 0; oh < 2; ++oh) {
                const int o = oh * 16 + lk;
                for (int ck = 0; ck < 5; ++ck) {
                    const int ti  = 2 * ck + (g2 >> 1);
                    const int tj0 = (g2 & 1) * 8;
                    unsigned int pk[4];
#pragma unroll
                    for (int ee = 0; ee < 4; ++ee) {
                        int tj_a = tj0 + 2 * ee, tj_b = tj_a + 1;
                        float va = (ti <= 8 && tj_a <= 8) ? kern[o * 1296 + ti * 9 + tj_a] : 0.f;
                        float vb = (ti <= 8 && tj_b <= 8) ? kern[o * 1296 + ti * 9 + tj_b] : 0.f;
                        pk[ee] = f2bf(va) | (f2bf(vb) << 16);
                    }
                    bpre[(oh * 5 + ck) * 64 + l] = (uint4v){pk[0], pk[1], pk[2], pk[3]};
                }
            }
        }
        return;
    }
    for (int idx = blockIdx.x * 256 + threadIdx.x; idx < XR_TOT_DW;
         idx += PREP_STRIDE) {
        int bc  = idx / XR_CH_DW;
        int rem = idx - bc * XR_CH_DW;
        int r   = rem / XR_RDW;
        int ccd = rem - r * XR_RDW;
        int cc  = 2 * ccd;
        const float* xp = x + (bc << 14) + ((r & 127) << 7);
        float v0 = xp[(132 - cc) & 127];
        float v1 = xp[(131 - cc) & 127];
        xr[idx] = f2bf(v0) | (f2bf(v1) << 16);
    }
}

// ---- main
__global__ __launch_bounds__(256, 2)
void optical_conv_69698729279498(const unsigned int* __restrict__ xr,
                                 const uint4v* __restrict__ bpre,
                                 float* __restrict__ out) {
    __shared__ __align__(16) unsigned short ldsb[16 * (CHB / 2)];  // 50688 B

    const int tid = threadIdx.x;
    const int l   = tid & 63;
    const int w   = tid >> 6;        // wave 0..3
    const int oh  = w & 1;           // o-half
    const int rh  = w >> 1;          // row within block's 2-row tile
    const int i0  = blockIdx.x * 2;  // first output row of tile
    const int b   = blockIdx.y;      // batch 0..7

    const int lk   = l & 15;         // A m-index / B,D o-index
    const int g    = (l >> 4) & 1;   // tj half for A
    const int hi32 = l >> 5;         // ti parity within chunk for A
    const int g2   = l >> 4;         // quad 0..3
    const int o    = oh * 16 + lk;

    // ---- staging: wave w DMAs channels 4w..4w+3 (contiguous slabs in xr)
    const int wstart = (i0 >= 4) ? (i0 - 4) : (i0 + 124);
    const char* xr8 = (const char*)xr;
#pragma unroll
    for (int cw = 0; cw < 4; ++cw) {
        const int ch = 4 * w + cw;
        const char* src = xr8 + ((size_t)((b * 16 + ch) * XR_ROWS + wstart)) * 288;
        char* dst = (char*)ldsb + ch * CHB;
        gload_lds16(src + 0 * 1024 + l * 16, dst + 0 * 1024);
        gload_lds16(src + 1 * 1024 + l * 16, dst + 1 * 1024);
        gload_lds16(src + 2 * 1024 + l * 16, dst + 2 * 1024);
        if (l < 6)   // tail: 3168 - 3072 = 96 B
            gload_lds16(src + 3072 + l * 16, dst + 3072);
    }

    // ---- B fragments: 5 coalesced dwordx4 loads (this wave's o-half)
    short8 Bf[5];
#pragma unroll
    for (int ck = 0; ck < 5; ++ck)
        Bf[ck] = __builtin_bit_cast(short8, bpre[(oh * 5 + ck) * 64 + l]);

    __syncthreads();   // the ONLY barrier (drains the global_load_lds queue)

    float4v acc[8];
#pragma unroll
    for (int p = 0; p < 8; ++p) acc[p] = (float4v){0.f, 0.f, 0.f, 0.f};
    const float4v zero4 = (float4v){0.f, 0.f, 0.f, 0.f};

    // chunk ck of channel c: byte (9 - 2ck - hi32 + rh)*288 + 240 - 16lk + 16g
    const char* lb = (const char*)ldsb
                   + (240 - 16 * lk + 16 * g) + (1 - hi32 + rh) * 288;

    for (int c = 0; c < 16; ++c) {
        // issue all 10 window reads up front (immediate ds offsets off lb)
        uint4v wa[5], wb[5];
#pragma unroll
        for (int ck = 0; ck < 5; ++ck) {
            const char* p = lb + (8 - 2 * ck) * 288;
            wa[ck] = *(const uint4v*)p;
            wb[ck] = *(const uint4v*)(p + 16);
        }
        float4v D[8];
#pragma unroll
        for (int ck = 0; ck < 5; ++ck) {
            unsigned int wnd[8] = {wa[ck].x, wa[ck].y, wa[ck].z, wa[ck].w,
                                   wb[ck].x, wb[ck].y, wb[ck].z, wb[ck].w};
            // all 8 phases: frag byte offsets 14,12,10,8,6,4,2,0 -> D[0..7]
            short8 f0 = FRAG_ODD(3),  f1 = FRAG_EVEN(3);
            short8 f2 = FRAG_ODD(2),  f3 = FRAG_EVEN(2);
            short8 f4 = FRAG_ODD(1),  f5 = FRAG_EVEN(1);
            short8 f6 = FRAG_ODD(0),  f7 = FRAG_EVEN(0);
            D[0] = __builtin_amdgcn_mfma_f32_16x16x32_bf16(f0, Bf[ck], ck ? D[0] : zero4, 0, 0, 0);
            D[1] = __builtin_amdgcn_mfma_f32_16x16x32_bf16(f1, Bf[ck], ck ? D[1] : zero4, 0, 0, 0);
            D[2] = __builtin_amdgcn_mfma_f32_16x16x32_bf16(f2, Bf[ck], ck ? D[2] : zero4, 0, 0, 0);
            D[3] = __builtin_amdgcn_mfma_f32_16x16x32_bf16(f3, Bf[ck], ck ? D[3] : zero4, 0, 0, 0);
            D[4] = __builtin_amdgcn_mfma_f32_16x16x32_bf16(f4, Bf[ck], ck ? D[4] : zero4, 0, 0, 0);
            D[5] = __builtin_amdgcn_mfma_f32_16x16x32_bf16(f5, Bf[ck], ck ? D[5] : zero4, 0, 0, 0);
            D[6] = __builtin_amdgcn_mfma_f32_16x16x32_bf16(f6, Bf[ck], ck ? D[6] : zero4, 0, 0, 0);
            D[7] = __builtin_amdgcn_mfma_f32_16x16x32_bf16(f7, Bf[ck], ck ? D[7] : zero4, 0, 0, 0);
        }
#pragma unroll
        for (int p = 0; p < 8; ++p)
#pragma unroll
            for (int e = 0; e < 4; ++e) acc[p][e] += fabsf(D[p][e]);
        lb += CHB;
    }

    // ---- epilogue: lane holds o = oh*16+lk, row i0+rh, pixels j = 32g2+8e+p
    const int i = i0 + rh;
    float* ob = out + ((((size_t)(b * 32 + o)) * 128 + i) << 7);
#pragma unroll
    for (int e = 0; e < 4; ++e) {
        float4v lo = (float4v){acc[0][e], acc[1][e], acc[2][e], acc[3][e]};
        float4v hi = (float4v){acc[4][e], acc[5][e], acc[6][e], acc[7][e]};
        *(float4v*)&ob[32 * g2 + 8 * e]     = lo;
        *(float4v*)&ob[32 * g2 + 8 * e + 4] = hi;
    }
}

extern "C" void kernel_launch(void* const* d_in, const int* in_sizes, int n_in,
                              void* d_out, int out_size, void* d_ws, size_t ws_size,
                              hipStream_t stream) {
    const float* x = (const float*)d_in[0];      // [8,16,128,128]
    const float* kern = (const float*)d_in[1];   // [32,16,9,9]
    float* out = (float*)d_out;                  // [8,32,128,128]
    unsigned int* xr = (unsigned int*)d_ws;                        // 5.09 MB
    uint4v* bpre = (uint4v*)((char*)d_ws + BPRE_OFF);              // +10 KB

    hipLaunchKernelGGL(optical_prep_69698729279498, dim3(PREP_BLOCKS + 1),
                       dim3(256), 0, stream, x, kern, xr, bpre);
    hipLaunchKernelGGL(optical_conv_69698729279498, dim3(64, 8), dim3(256),
                       0, stream, xr, bpre, out);
}